// Round 7
// baseline (277.135 us; speedup 1.0000x reference)
//
#include <hip/hip_runtime.h>

// Problem constants (from reference)
constexpr int kB   = 128;
constexpr int kU   = 4;
constexpr int kNBS = 64;
constexpr int kS   = 408;
constexpr int kS4  = kS / 4;                               // 102 float4 per row
constexpr unsigned kThreads =
    (unsigned)kB * kU * (kNBS / 16) * kS4;                 // 208,896 (16 rows/thread)
constexpr float kEmW     = 0.01f;
constexpr float kInvNRad = 1.0f / ((float)kB * kU * kNBS * kS);
constexpr float kInvNAtt = 1.0f / ((float)kB * kU * kS);

// Native clang vector type — required by __builtin_nontemporal_load.
typedef float vfloat4 __attribute__((ext_vector_type(4)));

// R15: R14 pipeline + amdgpu_waves_per_eu(3,3) to KILL the spills.
//
// Session ledger:
//  R8/R12 (256,3), NT, chunk=8 one-shot: 44.2-44.9 us, VGPR=84  <- champion
//  R9  plain loads (no NT):              79.5 us — L2 thrash. Keep NT.
//  R11 (256,6):                         126.0 us — spill (WRITE=162MB).
//  R13 rr[2][4] arrays:                 114.5 us — scratch (WRITE=120.8MB).
//  R14 named regs, (256,3):             116.5 us — IDENTICAL spill counters
//      (VGPR=84, WRITE=120.8MB). Diagnosis: 512/84≈6 -> the allocator
//      targets 6 waves/EU on its own; launch_bounds' 2nd arg is only a
//      MINIMUM and never lowers that ambition. It spills 512 B/thread of
//      tile buffers rather than drop occupancy. R8 fit 84 VGPRs only
//      because its loads could be sunk/serialized; the explicit pipeline
//      order demands ~150 live VGPRs.
//
// Fix: __attribute__((amdgpu_waves_per_eu(3,3))) pins min=max=3 waves/EU
// -> allocator knows occupancy >3 is worthless, uses the full ~170-VGPR
// budget. This finally lets the double-buffered pipeline exist in machine
// code: 16-32 NT loads continuously in flight per thread, 816 blocks
// (1.06 generations at 3 blocks/CU), atten re-reads halved vs champion.
// Tripwires (pre-committed):
//   VGPR>=128 + WRITE~51KB + dur 34-39us -> pipeline theory confirmed.
//   VGPR>=128 + WRITE~51KB + dur 44-47us -> service ceiling real; revert
//                                           to R12 and declare roofline.
//   VGPR~84  + WRITE in MB               -> compiler won't honor; revert.
//
// Mapping: tid in [0, 208896).
//   s4  = tid % 102                    (fastest dim -> coalesced)
//   rem = tid / 102  in [0, 2048)
//   sub = rem % 4, bu = rem / 4        (bu in [0,512) = b*U+u)
//   rows r = bu*64 + sub*16 + t*4 + j, t=0..3, j=0..3; q = r*102 + s4
//   atten a = bu*102 + s4 — loaded once, reused for all 16 rows.

#define NTLOAD(p) __builtin_nontemporal_load(p)

// Issue one 4-row tile into buffer P (16 NT loads, row-interleaved so
// consumption order matches issue order -> incremental vmcnt waits).
#define ISSUE_TILE(P, T)                                                  \
  {                                                                       \
    const unsigned q0_ = qbase + (unsigned)(T) * (4u * 102u);             \
    P##rr0 = NTLOAD(&rad_re[q0_]);                                        \
    P##ri0 = NTLOAD(&rad_im[q0_]);                                        \
    P##tr0 = NTLOAD(&tgt_re[q0_]);                                        \
    P##ti0 = NTLOAD(&tgt_im[q0_]);                                        \
    P##rr1 = NTLOAD(&rad_re[q0_ + 102u]);                                 \
    P##ri1 = NTLOAD(&rad_im[q0_ + 102u]);                                 \
    P##tr1 = NTLOAD(&tgt_re[q0_ + 102u]);                                 \
    P##ti1 = NTLOAD(&tgt_im[q0_ + 102u]);                                 \
    P##rr2 = NTLOAD(&rad_re[q0_ + 204u]);                                 \
    P##ri2 = NTLOAD(&rad_im[q0_ + 204u]);                                 \
    P##tr2 = NTLOAD(&tgt_re[q0_ + 204u]);                                 \
    P##ti2 = NTLOAD(&tgt_im[q0_ + 204u]);                                 \
    P##rr3 = NTLOAD(&rad_re[q0_ + 306u]);                                 \
    P##ri3 = NTLOAD(&rad_im[q0_ + 306u]);                                 \
    P##tr3 = NTLOAD(&tgt_re[q0_ + 306u]);                                 \
    P##ti3 = NTLOAD(&tgt_im[q0_ + 306u]);                                 \
  }

// Consume one row (4 components). Math identical to champion.
#define ROW(RR, RI, TR, TI)                                               \
  {                                                                       \
    _Pragma("unroll")                                                     \
    for (int c = 0; c < 4; ++c) {                                         \
      const float r_r = (RR)[c], r_i = (RI)[c];                           \
      const float pr = ar[c] * r_r - ai[c] * r_i;                         \
      const float pi = ar[c] * r_i + ai[c] * r_r;                         \
      const float dr = pr - (TR)[c];                                      \
      const float di = pi - (TI)[c];                                      \
      recv = fmaf((dr * dr + di * di), w[c], recv);                       \
      float rm = sqrtf(fmaf(r_r, r_r, r_i * r_i)) - 10.0f;                \
      rm = fmaxf(rm, 0.0f);                                               \
      em_rad = fmaf(rm, rm, em_rad);                                      \
    }                                                                     \
  }

#define CONSUME_TILE(P)                                                   \
  ROW(P##rr0, P##ri0, P##tr0, P##ti0)                                     \
  ROW(P##rr1, P##ri1, P##tr1, P##ti1)                                     \
  ROW(P##rr2, P##ri2, P##tr2, P##ti2)                                     \
  ROW(P##rr3, P##ri3, P##tr3, P##ti3)

__global__ void __launch_bounds__(256)
__attribute__((amdgpu_waves_per_eu(3, 3)))
prism_loss_kernel(const vfloat4* __restrict__ atten_re,
                  const vfloat4* __restrict__ atten_im,
                  const vfloat4* __restrict__ rad_re,
                  const vfloat4* __restrict__ rad_im,
                  const vfloat4* __restrict__ tgt_re,
                  const vfloat4* __restrict__ tgt_im,
                  const vfloat4* __restrict__ weights,
                  float* __restrict__ out)
{
    const unsigned tid   = blockIdx.x * 256 + threadIdx.x;  // grid sized exactly
    const unsigned rem   = tid / 102u;                      // magic-mul div
    const unsigned s4    = tid - rem * 102u;
    const unsigned sub   = rem & 3u;
    const unsigned bu    = rem >> 2;
    const unsigned qbase = (bu * 64u + sub * 16u) * 102u + s4;
    const unsigned abase = bu * 102u + s4;
    const bool do_att = (sub == 0u);

    const vfloat4 w  = weights[s4];
    const vfloat4 ar = atten_re[abase];
    const vfloat4 ai = atten_im[abase];

    // Two named tile buffers: 32 vfloat4 = 128 VGPRs payload, all
    // compile-time register names.
    vfloat4 Arr0, Ari0, Atr0, Ati0, Arr1, Ari1, Atr1, Ati1;
    vfloat4 Arr2, Ari2, Atr2, Ati2, Arr3, Ari3, Atr3, Ati3;
    vfloat4 Brr0, Bri0, Btr0, Bti0, Brr1, Bri1, Btr1, Bti1;
    vfloat4 Brr2, Bri2, Btr2, Bti2, Brr3, Bri3, Btr3, Bti3;

    float recv   = 0.0f;
    float em_rad = 0.0f;
    float em_att = 0.0f;

    // Software pipeline: 1 tile ahead in steady state.
    ISSUE_TILE(A, 0)
    ISSUE_TILE(B, 1)
    CONSUME_TILE(A)
    ISSUE_TILE(A, 2)
    CONSUME_TILE(B)
    ISSUE_TILE(B, 3)
    CONSUME_TILE(A)
    CONSUME_TILE(B)

    if (do_att) {
        #pragma unroll
        for (int c = 0; c < 4; ++c) {
            float am = sqrtf(fmaf(ar[c], ar[c], ai[c] * ai[c])) - 1.0f;
            am = fmaxf(am, 0.0f);
            em_att = fmaf(am, am, em_att);
        }
    }

    float acc = recv + kEmW * (em_rad * kInvNRad + em_att * kInvNAtt);

    // Wave-64 reduction.
    #pragma unroll
    for (int off = 32; off > 0; off >>= 1)
        acc += __shfl_down(acc, off, 64);

    __shared__ float sdata[4];
    const int lane = threadIdx.x & 63;
    const int wave = threadIdx.x >> 6;
    if (lane == 0) sdata[wave] = acc;
    __syncthreads();
    if (threadIdx.x == 0) {
        atomicAdd(out, sdata[0] + sdata[1] + sdata[2] + sdata[3]);
    }
}

extern "C" void kernel_launch(void* const* d_in, const int* in_sizes, int n_in,
                              void* d_out, int out_size, void* d_ws, size_t ws_size,
                              hipStream_t stream) {
    const vfloat4* atten_re = (const vfloat4*)d_in[0];
    const vfloat4* atten_im = (const vfloat4*)d_in[1];
    const vfloat4* rad_re   = (const vfloat4*)d_in[2];
    const vfloat4* rad_im   = (const vfloat4*)d_in[3];
    const vfloat4* tgt_re   = (const vfloat4*)d_in[4];
    const vfloat4* tgt_im   = (const vfloat4*)d_in[5];
    const vfloat4* weights  = (const vfloat4*)d_in[6];
    float* out = (float*)d_out;

    // d_out is re-poisoned to 0xAA before every timed launch; zero it.
    (void)hipMemsetAsync(out, 0, sizeof(float), stream);

    // 816 blocks * 256 threads == kThreads exactly (no bounds checks needed).
    prism_loss_kernel<<<(int)(kThreads / 256), 256, 0, stream>>>(
        atten_re, atten_im, rad_re, rad_im, tgt_re, tgt_im, weights, out);
}

// Round 8
// 208.928 us; speedup vs baseline: 1.3265x; 1.3265x over previous
//
#include <hip/hip_runtime.h>

// Problem constants (from reference)
constexpr int kB   = 128;
constexpr int kU   = 4;
constexpr int kNBS = 64;
constexpr int kS   = 408;
constexpr int kS4  = kS / 4;                               // 102 float4 per row
constexpr unsigned kNQ = (unsigned)kB * kU * kNBS * kS4;   // 3,342,336 float4 groups
constexpr int kChunk   = 8;                                // NBS rows per thread
constexpr unsigned kThreads = kNQ / kChunk;                // 417,792 threads
constexpr float kEmW     = 0.01f;
constexpr float kInvNRad = 1.0f / ((float)kB * kU * kNBS * kS);
constexpr float kInvNAtt = 1.0f / ((float)kB * kU * kS);

// Native clang vector type — required by __builtin_nontemporal_load.
typedef float vfloat4 __attribute__((ext_vector_type(4)));

// R16 == R8/R12 champion restored (final state).
//
// Session ledger:
//  R8/R12 (256,3), NT, chunk=8 one-shot: 44.2-44.9 us, VGPR=84  <- champion
//  R9  plain loads (no NT):              79.5 us — L2 thrash. Keep NT.
//  R11 (256,6):                         126.0 us — spill (WRITE=162MB).
//  R13 rr[2][4] array double-buffer:    114.5 us — scratch-demoted.
//  R14 named-reg double-buffer (256,3): 116.5 us — same spill (VGPR=84,
//      WRITE=120.8MB byte-identical).
//  R15 R14 + amdgpu_waves_per_eu(3,3):  137.6 us — attribute seen
//      (SGPR 32->112) but SAME spill signature; allocator refuses to keep
//      the 128-VGPR double-buffer live under any budget granted.
//
// Roofline argument (why this is final):
//  * HBM service rate for this NT 4-stream pattern is ~2.7-3.0 TB/s and
//    nearly invariant to: occupancy (R8 ~7 waves/CU -> 2.67; R11 50% occ
//    -> 2.95 TB/s, +10% for 2.4x parallelism), per-wave MLP (8->16 +23%,
//    16->32 neutral), cache policy (NT vs plain: FETCH 117 vs 112 MB),
//    and software pipelining (3 attempts, compiler-refused; <=10% headroom
//    per the occupancy-invariance evidence anyway).
//  * 215.6 MB logical = 117 MB HBM @ ~2.7 TB/s + ~99 MB LLC @ ~2.2 TB/s
//    served concurrently -> ~44 us. Measured 44.2-44.9 us.
//
// Mapping: tid in [0, 417792).
//   s4    = tid % 102                  (fastest dim -> coalesced)
//   rem   = tid / 102   in [0, 4096)
//   chunk = rem % 8, bu = rem / 8      (bu in [0,512) = b*U+u)
//   rows r = bu*64 + chunk*8 + j, j=0..7; streaming q_j = r*102 + s4
//   atten a = bu*102 + s4 — loaded once, reused for all 8 rows.
__global__ void __launch_bounds__(256, 3)
prism_loss_kernel(const vfloat4* __restrict__ atten_re,
                  const vfloat4* __restrict__ atten_im,
                  const vfloat4* __restrict__ rad_re,
                  const vfloat4* __restrict__ rad_im,
                  const vfloat4* __restrict__ tgt_re,
                  const vfloat4* __restrict__ tgt_im,
                  const vfloat4* __restrict__ weights,
                  float* __restrict__ out)
{
    const unsigned tid   = blockIdx.x * 256 + threadIdx.x;  // grid sized exactly
    const unsigned rem   = tid / 102u;                      // magic-mul div
    const unsigned s4    = tid - rem * 102u;
    const unsigned chunk = rem & 7u;
    const unsigned bu    = rem >> 3;
    const unsigned qbase = (bu * 64u + chunk * 8u) * 102u + s4;
    const unsigned abase = bu * 102u + s4;
    const bool do_att = (chunk == 0u);

    const vfloat4 w  = weights[s4];
    const vfloat4 ar = atten_re[abase];
    const vfloat4 ai = atten_im[abase];

    // Single batch: all 32 NT loads issued before any use. The scheduler
    // sinks/staggers them into ~half-batches that fit 84 VGPRs — measured
    // best configuration for this pattern.
    vfloat4 rr[8], ri[8], tr[8], ti[8];
    #pragma unroll
    for (int j = 0; j < 8; ++j) {
        const unsigned q = qbase + (unsigned)j * 102u;
        rr[j] = __builtin_nontemporal_load(&rad_re[q]);
        ri[j] = __builtin_nontemporal_load(&rad_im[q]);
        tr[j] = __builtin_nontemporal_load(&tgt_re[q]);
        ti[j] = __builtin_nontemporal_load(&tgt_im[q]);
    }

    float recv   = 0.0f;
    float em_rad = 0.0f;
    float em_att = 0.0f;

    // Consume in issue order -> compiler emits incremental vmcnt(N) waits.
    #pragma unroll
    for (int j = 0; j < 8; ++j) {
        #pragma unroll
        for (int c = 0; c < 4; ++c) {
            const float a_r = ar[c], a_i = ai[c];
            const float r_r = rr[j][c], r_i = ri[j][c];
            const float pr = a_r * r_r - a_i * r_i;
            const float pi = a_r * r_i + a_i * r_r;
            const float dr = pr - tr[j][c];
            const float di = pi - ti[j][c];
            recv = fmaf((dr * dr + di * di), w[c], recv);
            float rm = sqrtf(fmaf(r_r, r_r, r_i * r_i)) - 10.0f;
            rm = fmaxf(rm, 0.0f);
            em_rad = fmaf(rm, rm, em_rad);
        }
    }

    if (do_att) {
        #pragma unroll
        for (int c = 0; c < 4; ++c) {
            float am = sqrtf(fmaf(ar[c], ar[c], ai[c] * ai[c])) - 1.0f;
            am = fmaxf(am, 0.0f);
            em_att = fmaf(am, am, em_att);
        }
    }

    float acc = recv + kEmW * (em_rad * kInvNRad + em_att * kInvNAtt);

    // Wave-64 reduction.
    #pragma unroll
    for (int off = 32; off > 0; off >>= 1)
        acc += __shfl_down(acc, off, 64);

    __shared__ float sdata[4];
    const int lane = threadIdx.x & 63;
    const int wave = threadIdx.x >> 6;
    if (lane == 0) sdata[wave] = acc;
    __syncthreads();
    if (threadIdx.x == 0) {
        atomicAdd(out, sdata[0] + sdata[1] + sdata[2] + sdata[3]);
    }
}

extern "C" void kernel_launch(void* const* d_in, const int* in_sizes, int n_in,
                              void* d_out, int out_size, void* d_ws, size_t ws_size,
                              hipStream_t stream) {
    const vfloat4* atten_re = (const vfloat4*)d_in[0];
    const vfloat4* atten_im = (const vfloat4*)d_in[1];
    const vfloat4* rad_re   = (const vfloat4*)d_in[2];
    const vfloat4* rad_im   = (const vfloat4*)d_in[3];
    const vfloat4* tgt_re   = (const vfloat4*)d_in[4];
    const vfloat4* tgt_im   = (const vfloat4*)d_in[5];
    const vfloat4* weights  = (const vfloat4*)d_in[6];
    float* out = (float*)d_out;

    // d_out is re-poisoned to 0xAA before every timed launch; zero it.
    (void)hipMemsetAsync(out, 0, sizeof(float), stream);

    // 1632 blocks * 256 threads == kThreads exactly (no bounds checks needed).
    prism_loss_kernel<<<(int)(kThreads / 256), 256, 0, stream>>>(
        atten_re, atten_im, rad_re, rad_im, tgt_re, tgt_im, weights, out);
}